// Round 1
// baseline (410.163 us; speedup 1.0000x reference)
//
#include <hip/hip_runtime.h>

static constexpr int N_ROWS = 524288;
static constexpr int C_COLS = 128;
static constexpr float CLIP_V = 1e-10f;
static constexpr int BLOCKS = 2048;   // 2048*256 == 524288: exactly 1 row/thread, 32 waves/CU
static constexpr int THREADS = 256;

__device__ __forceinline__ float block_reduce_sum(float v) {
    // 64-lane wave reduction (CDNA wave = 64)
    #pragma unroll
    for (int off = 32; off > 0; off >>= 1)
        v += __shfl_down(v, off, 64);
    __shared__ float s[THREADS / 64];
    const int lane = threadIdx.x & 63;
    const int wave = threadIdx.x >> 6;
    if (lane == 0) s[wave] = v;
    __syncthreads();
    if (wave == 0) {
        v = (lane < THREADS / 64) ? s[lane] : 0.0f;
        #pragma unroll
        for (int off = (THREADS / 64) / 2; off > 0; off >>= 1)
            v += __shfl_down(v, off, 64);
    }
    return v; // valid in threadIdx.x == 0
}

__global__ __launch_bounds__(THREADS)
void logloss_fused(const float* __restrict__ inp,
                   const int* __restrict__ tgt,
                   const float* __restrict__ w,
                   float* __restrict__ partial,
                   unsigned int* __restrict__ counter,
                   float* __restrict__ out) {
    // stage weight[128] in LDS (512 B)
    __shared__ float ws[C_COLS];
    for (int j = threadIdx.x; j < C_COLS; j += THREADS) ws[j] = w[j];
    __syncthreads();

    // exact cover: one row per thread (BLOCKS*THREADS == N_ROWS)
    const int i = blockIdx.x * THREADS + threadIdx.x;
    const int t = tgt[i];                          // coalesced 4B/lane
    const float x = inp[(size_t)i * C_COLS + t];   // one 4B gather -> one 64B line/row (floor)
    const float acc = __logf(fmaxf(x, CLIP_V)) * ws[t];

    const float b = block_reduce_sum(acc);

    // last-block-done final reduction (replaces the second kernel launch).
    // Reduction order is bitwise-identical to the previous logloss_final.
    __shared__ bool amLast;
    if (threadIdx.x == 0) {
        // agent-scope release store: publish past this XCD's (non-coherent) L2
        __hip_atomic_store(&partial[blockIdx.x], b,
                           __ATOMIC_RELEASE, __HIP_MEMORY_SCOPE_AGENT);
        const unsigned prev = __hip_atomic_fetch_add(counter, 1u,
                           __ATOMIC_ACQ_REL, __HIP_MEMORY_SCOPE_AGENT);
        amLast = (prev == (unsigned)(gridDim.x - 1));
    }
    __syncthreads();

    if (amLast) {
        float v = 0.0f;
        for (int k = threadIdx.x; k < BLOCKS; k += THREADS)
            v += __hip_atomic_load(&partial[k],
                                   __ATOMIC_RELAXED, __HIP_MEMORY_SCOPE_AGENT);
        const float sfin = block_reduce_sum(v);
        if (threadIdx.x == 0) out[0] = -sfin / (float)N_ROWS;
    }
}

extern "C" void kernel_launch(void* const* d_in, const int* in_sizes, int n_in,
                              void* d_out, int out_size, void* d_ws, size_t ws_size,
                              hipStream_t stream) {
    const float* inp = (const float*)d_in[0];
    const int* tgt = (const int*)d_in[1];
    const float* w = (const float*)d_in[2];
    float* out = (float*)d_out;

    float* partial = (float*)d_ws;                         // BLOCKS * 4 B
    unsigned int* counter = (unsigned int*)((char*)d_ws + BLOCKS * sizeof(float));

    // workspace is poisoned each iteration -> counter must be re-zeroed in-graph
    hipMemsetAsync(counter, 0, sizeof(unsigned int), stream);
    logloss_fused<<<BLOCKS, THREADS, 0, stream>>>(inp, tgt, w, partial, counter, out);
}

// Round 2
// 316.174 us; speedup vs baseline: 1.2973x; 1.2973x over previous
//
#include <hip/hip_runtime.h>

static constexpr int N_ROWS = 524288;
static constexpr int C_COLS = 128;
static constexpr float CLIP_V = 1e-10f;
static constexpr int BLOCKS = 2048;   // 524288 threads = 1 row/thread, 32 waves/CU
static constexpr int THREADS = 256;

__device__ __forceinline__ float block_reduce_sum(float v) {
    // 64-lane wave reduction (CDNA wave = 64)
    #pragma unroll
    for (int off = 32; off > 0; off >>= 1)
        v += __shfl_down(v, off, 64);
    __shared__ float s[THREADS / 64];
    const int lane = threadIdx.x & 63;
    const int wave = threadIdx.x >> 6;
    if (lane == 0) s[wave] = v;
    __syncthreads();
    if (wave == 0) {
        v = (lane < THREADS / 64) ? s[lane] : 0.0f;
        #pragma unroll
        for (int off = (THREADS / 64) / 2; off > 0; off >>= 1)
            v += __shfl_down(v, off, 64);
    }
    return v; // valid in threadIdx.x == 0
}

__global__ __launch_bounds__(THREADS)
void logloss_partial(const float* __restrict__ inp,
                     const int* __restrict__ tgt,
                     const float* __restrict__ w,
                     float* __restrict__ partial) {
    // stage weight[128] in LDS (512 B)
    __shared__ float ws[C_COLS];
    for (int j = threadIdx.x; j < C_COLS; j += THREADS) ws[j] = w[j];
    __syncthreads();

    const int tid = blockIdx.x * THREADS + threadIdx.x;
    const int stride = gridDim.x * THREADS;

    float acc = 0.0f; // sum of log(clip(x)) * w (negated at the end)
    for (int i = tid; i < N_ROWS; i += stride) {
        const int t = tgt[i];                          // coalesced 4B/lane
        const float x = inp[(size_t)i * C_COLS + t];   // one 4B gather per row
        acc += __logf(fmaxf(x, CLIP_V)) * ws[t];
    }

    const float b = block_reduce_sum(acc);
    if (threadIdx.x == 0) partial[blockIdx.x] = b;
}

__global__ __launch_bounds__(THREADS)
void logloss_final(const float* __restrict__ partial, float* __restrict__ out) {
    float v = 0.0f;
    for (int i = threadIdx.x; i < BLOCKS; i += THREADS) v += partial[i];
    const float s = block_reduce_sum(v);
    if (threadIdx.x == 0) out[0] = -s / (float)N_ROWS;
}

// NOTE (R1 post-mortem): a fused last-block-done variant with agent-scope
// release/acquire atomics regressed +94 us — on gfx950 each agent-scope
// release/acquire pair costs an L2 writeback/invalidate per block (2048x),
// and the invalidates also evict lines concurrent blocks were streaming.
// Two plain launches are strictly cheaper. Do not re-fuse via atomics.

extern "C" void kernel_launch(void* const* d_in, const int* in_sizes, int n_in,
                              void* d_out, int out_size, void* d_ws, size_t ws_size,
                              hipStream_t stream) {
    const float* inp = (const float*)d_in[0];
    const int* tgt = (const int*)d_in[1];
    const float* w = (const float*)d_in[2];
    float* out = (float*)d_out;
    float* partial = (float*)d_ws; // BLOCKS * 4 bytes

    logloss_partial<<<BLOCKS, THREADS, 0, stream>>>(inp, tgt, w, partial);
    logloss_final<<<1, THREADS, 0, stream>>>(partial, out);
}